// Round 5
// baseline (75.259 us; speedup 1.0000x reference)
//
#include <hip/hip_runtime.h>

// Persistence-image kernel, MI355X — fused, max-occupancy, min3 inner loop.
// S=128, I=32 intervals, C=32 corners, R=30 -> G=900.
// img[s,g] = sum_i w_i^2 * exp(-200 * max(min_c |g-b_ic|^2, min_c |g-d_ic|^2))
// |g-p|^2 = (|p|^2 - 2 g.p) + |g|^2 -> 8 fma + 2 v_min3 per (q,j) (was 12 ops).
// Block = (sample, 2-interval chunk, g-half): 4096 blocks -> 16 blocks/CU,
// 8 waves/SIMD (HW max), VGPR capped via __launch_bounds__(128,8).

#define RES 30
#define GPTS 900
#define NS 128
#define INV29 (1.0f / 29.0f)

__global__ __launch_bounds__(128, 8) void pimg_kernel(
    const float* __restrict__ births, const float* __restrict__ deaths,
    float* __restrict__ out)
{
    const int bid = blockIdx.x;
    const int s   = bid >> 5;
    const int i0  = ((bid >> 1) & 15) * 2;
    const int gh  = bid & 1;
    const int tid = threadIdx.x;

    __shared__ __align__(16) float Bqx[64], Bqy[64], Br[64];
    __shared__ __align__(16) float Dqx[64], Dqy[64], Dr[64];
    __shared__ float wred[64];
    __shared__ float red[2][4];
    __shared__ float box[4];
    __shared__ float w2s[2];

    // ---- corner transform for this block's 2 intervals (threads 0..63)
    if (tid < 64) {
        const size_t base = (size_t)s * 1024 + (size_t)i0 * 32 + tid;
        const float2 pb = ((const float2*)births)[base];
        Bqx[tid] = -2.f * pb.x; Bqy[tid] = -2.f * pb.y; Br[tid] = pb.x * pb.x + pb.y * pb.y;
        const float2 pd = ((const float2*)deaths)[base];
        Dqx[tid] = -2.f * pd.x; Dqy[tid] = -2.f * pd.y; Dr[tid] = pd.x * pd.x + pd.y * pd.y;
        wred[tid] = fmaxf(fabsf(pd.x - pb.x), fabsf(pd.y - pb.y));
    }

    // ---- redundant per-block bbox over all 2048 points of sample s
    {
        const float4* b4 = (const float4*)(births + (size_t)s * 2048);
        const float4* d4 = (const float4*)(deaths + (size_t)s * 2048);
        float mnx = 3e38f, mny = 3e38f, mxx = -3e38f, mxy = -3e38f;
        #pragma unroll
        for (int k = 0; k < 4; ++k) {
            float4 f = b4[tid + 128 * k];
            mnx = fminf(mnx, fminf(f.x, f.z)); mxx = fmaxf(mxx, fmaxf(f.x, f.z));
            mny = fminf(mny, fminf(f.y, f.w)); mxy = fmaxf(mxy, fmaxf(f.y, f.w));
            float4 g = d4[tid + 128 * k];
            mnx = fminf(mnx, fminf(g.x, g.z)); mxx = fmaxf(mxx, fmaxf(g.x, g.z));
            mny = fminf(mny, fminf(g.y, g.w)); mxy = fmaxf(mxy, fmaxf(g.y, g.w));
        }
        #pragma unroll
        for (int off = 32; off > 0; off >>= 1) {
            mnx = fminf(mnx, __shfl_down(mnx, off));
            mny = fminf(mny, __shfl_down(mny, off));
            mxx = fmaxf(mxx, __shfl_down(mxx, off));
            mxy = fmaxf(mxy, __shfl_down(mxy, off));
        }
        const int wave = tid >> 6, lane = tid & 63;
        if (lane == 0) { red[wave][0] = mnx; red[wave][1] = mny; red[wave][2] = mxx; red[wave][3] = mxy; }
    }
    __syncthreads();

    if (tid == 0) {
        const float a = fminf(red[0][0], red[1][0]);
        const float b = fminf(red[0][1], red[1][1]);
        const float c = fmaxf(red[0][2], red[1][2]);
        const float d = fmaxf(red[0][3], red[1][3]);
        const float mgx = 0.1f * (c - a), mgy = 0.1f * (d - b);
        box[0] = a - mgx; box[1] = b - mgy; box[2] = c + mgx; box[3] = d + mgy;
    }
    if (tid < 2) {  // deterministic serial sum of 32 per-corner weights
        float ssum = 0.f;
        #pragma unroll
        for (int k = 0; k < 32; ++k) ssum += wred[tid * 32 + k];
        const float w = ssum * (1.0f / 32.0f);
        w2s[tid] = w * w;
    }
    __syncthreads();

    const float lox = box[0], loy = box[1];
    const float sx  = (box[2] - lox) * INV29;
    const float sy  = (box[3] - loy) * INV29;

    // j-interleaved g assignment: g = tid + 128*(2j+gh) -> balanced halves
    float gx[4], gy[4], acc[4];
    #pragma unroll
    for (int j = 0; j < 4; ++j) {
        const int g  = tid + 128 * (2 * j + gh);
        const int ix = g / RES, iy = g - ix * RES;
        gx[j]  = lox + (float)ix * sx;
        gy[j]  = loy + (float)iy * sy;
        acc[j] = 0.f;
    }

    const float4* Bqx4 = (const float4*)Bqx;
    const float4* Bqy4 = (const float4*)Bqy;
    const float4* Br4  = (const float4*)Br;
    const float4* Dqx4 = (const float4*)Dqx;
    const float4* Dqy4 = (const float4*)Dqy;
    const float4* Dr4  = (const float4*)Dr;

    #pragma unroll 1
    for (int il = 0; il < 2; ++il) {
        float mb[4], md[4];
        #pragma unroll
        for (int j = 0; j < 4; ++j) { mb[j] = 3e38f; md[j] = 3e38f; }

        #pragma unroll
        for (int q = 0; q < 8; ++q) {
            const float4 X  = Bqx4[il * 8 + q];
            const float4 Y  = Bqy4[il * 8 + q];
            const float4 Rr = Br4[il * 8 + q];
            #pragma unroll
            for (int j = 0; j < 4; ++j) {
                float a0 = fmaf(X.x, gx[j], Rr.x); a0 = fmaf(Y.x, gy[j], a0);
                float a1 = fmaf(X.y, gx[j], Rr.y); a1 = fmaf(Y.y, gy[j], a1);
                float a2 = fmaf(X.z, gx[j], Rr.z); a2 = fmaf(Y.z, gy[j], a2);
                float a3 = fmaf(X.w, gx[j], Rr.w); a3 = fmaf(Y.w, gy[j], a3);
                // chain matches 2x v_min3_f32: min3(a0,a1,a2) -> min3(.,a3,mb)
                mb[j] = fminf(fminf(fminf(fminf(a0, a1), a2), a3), mb[j]);
            }
        }
        #pragma unroll
        for (int q = 0; q < 8; ++q) {
            const float4 X  = Dqx4[il * 8 + q];
            const float4 Y  = Dqy4[il * 8 + q];
            const float4 Rr = Dr4[il * 8 + q];
            #pragma unroll
            for (int j = 0; j < 4; ++j) {
                float a0 = fmaf(X.x, gx[j], Rr.x); a0 = fmaf(Y.x, gy[j], a0);
                float a1 = fmaf(X.y, gx[j], Rr.y); a1 = fmaf(Y.y, gy[j], a1);
                float a2 = fmaf(X.z, gx[j], Rr.z); a2 = fmaf(Y.z, gy[j], a2);
                float a3 = fmaf(X.w, gx[j], Rr.w); a3 = fmaf(Y.w, gy[j], a3);
                md[j] = fminf(fminf(fminf(fminf(a0, a1), a2), a3), md[j]);
            }
        }

        const float w2 = w2s[il];
        #pragma unroll
        for (int j = 0; j < 4; ++j) {
            const float gg = gx[j] * gx[j] + gy[j] * gy[j];  // recomputed: saves VGPRs
            const float t  = fmaxf(mb[j], md[j]) + gg;
            acc[j] = fmaf(w2, __expf(-200.0f * t), acc[j]);
        }
    }

    #pragma unroll
    for (int j = 0; j < 4; ++j) {
        const int g = tid + 128 * (2 * j + gh);
        if (g < GPTS) atomicAdd(&out[(size_t)s * GPTS + g], acc[j]);
    }
}

extern "C" void kernel_launch(void* const* d_in, const int* in_sizes, int n_in,
                              void* d_out, int out_size, void* d_ws, size_t ws_size,
                              hipStream_t stream) {
    const float* births = (const float*)d_in[0];
    const float* deaths = (const float*)d_in[1];
    float* out = (float*)d_out;

    hipMemsetAsync(out, 0, (size_t)out_size * sizeof(float), stream);
    pimg_kernel<<<NS * 32, 128, 0, stream>>>(births, deaths, out);
}